// Round 2
// baseline (99.682 us; speedup 1.0000x reference)
//
#include <hip/hip_runtime.h>

constexpr int B = 64, N = 8732, C = 21, M = 16;
constexpr int BN = B * N;
constexpr int TROW = 1 + 6 * M; // 97

struct Ctl {
  unsigned pnum;        // count of positive targets
  unsigned validCount;  // count of valid targets
  float posCE;          // sum of -logp[cls] over positives
  float bboxNum;        // smooth-L1 numerator
  float negBelow;       // sum of -logp0 over keys in bins < t1 (all selected)
  unsigned t1, r1;      // level-1 bin and remaining rank within it
  unsigned candCount;   // number of keys in bin t1
};

__device__ __forceinline__ unsigned f2key(float f) {
  unsigned u = __float_as_uint(f);
  return (u & 0x80000000u) ? ~u : (u | 0x80000000u);
}
__device__ __forceinline__ float key2f(unsigned k) {
  unsigned u = (k & 0x80000000u) ? (k ^ 0x80000000u) : ~k;
  return __uint_as_float(u);
}

// ---- zero scratch (1 block) ----
__global__ __launch_bounds__(256) void k_zero(unsigned* __restrict__ hist1,
                                              Ctl* __restrict__ ctl) {
  int tid = threadIdx.x;
  for (int i = tid; i < 4096; i += 256) hist1[i] = 0;
  if (tid == 0) {
    ctl->pnum = 0; ctl->validCount = 0;
    ctl->posCE = 0.f; ctl->bboxNum = 0.f; ctl->negBelow = 0.f;
    ctl->candCount = 0;
  }
}

// ---- main: logp0 per anchor -> keys + level-1 histogram; block x==0 also
// ---- processes the 16 targets of its batch (pos CE + bbox smooth-L1) ----
__global__ __launch_bounds__(256) void k_main(
    const float* __restrict__ conf, const float* __restrict__ bbox,
    const float* __restrict__ target, const float* __restrict__ pred,
    unsigned* __restrict__ keys, unsigned* __restrict__ hist1,
    Ctl* __restrict__ ctl) {
  __shared__ __align__(16) float srow[256 * C];
  __shared__ unsigned shist[4096];
  __shared__ int sk[M];
  int b = blockIdx.y;
  int n0 = blockIdx.x * 256;
  int tid = threadIdx.x;

  for (int i = tid; i < 4096; i += 256) shist[i] = 0;
  const float* tr = target + (size_t)b * TROW;
  if (tid < M) {
    int num = (int)tr[0];
    int k = (int)tr[1 + 6 * tid + 5];
    sk[tid] = (tid < num) ? k : -1;
  }
  __syncthreads();

  int rows = min(256, N - n0);
  const float* gbase = conf + ((size_t)b * N + n0) * C;
  if (rows == 256) {
    const float4* g4 = (const float4*)gbase;
    float4* s4 = (float4*)srow;
    for (int i = tid; i < 256 * C / 4; i += 256) s4[i] = g4[i];
  } else {
    int nflt = rows * C;
    for (int i = tid; i < nflt; i += 256) srow[i] = gbase[i];
  }
  __syncthreads();

  if (tid < rows) {
    int n = n0 + tid;
    const float* x = srow + tid * C;
    float mx = x[0];
    for (int c = 1; c < C; c++) mx = fmaxf(mx, x[c]);
    float s = 0.f;
    for (int c = 0; c < C; c++) s += __expf(x[c] - mx);
    float logp0 = x[0] - mx - __logf(s);
    bool assigned = false;
    for (int j = 0; j < M; j++) assigned |= (sk[j] == n);
    unsigned key = 0xFFFFFFFFu;
    if (!assigned) {
      key = f2key(logp0);
      atomicAdd(&shist[key >> 20], 1u);
    }
    keys[(size_t)b * N + n] = key;
  }

  // fused per-batch target processing (one block per batch does it)
  if (blockIdx.x == 0 && tid < M) {
    int num = (int)tr[0];
    if (tid < num) {
      const float* e = tr + 1 + 6 * tid;
      int cls = (int)e[0];
      float tx1 = e[1], ty1 = e[2], tx2 = e[3], ty2 = e[4];
      int k = (int)e[5];
      float p0 = pred[k * 4 + 0], p1 = pred[k * 4 + 1];
      float p2 = pred[k * 4 + 2], p3 = pred[k * 4 + 3];
      float pw = p2 - p0, ph = p3 - p1;
      float pcx = (p0 + p2) * 0.5f, pcy = (p1 + p3) * 0.5f;
      float tw = tx2 - tx1, th = ty2 - ty1;
      float tcx = (tx1 + tx2) * 0.5f, tcy = (ty1 + ty2) * 0.5f;
      float ebv[4];
      ebv[0] = (tcx - pcx) / pw;
      ebv[1] = (tcy - pcy) / ph;
      ebv[2] = __logf(tw / pw);
      ebv[3] = __logf(th / ph);
      const float* bo = bbox + ((size_t)b * N + k) * 4;
      float sl = 0.f;
      for (int j = 0; j < 4; j++) {
        float d = bo[j] - ebv[j];
        float ad = fabsf(d);
        sl += (ad < 1.f) ? 0.5f * d * d : ad - 0.5f;
      }
      atomicAdd(&ctl->bboxNum, sl);
      atomicAdd(&ctl->validCount, 1u);
      if (cls > 0) {
        atomicAdd(&ctl->pnum, 1u);
        const float* x = conf + ((size_t)b * N + k) * C;
        float mx = x[0];
        for (int c = 1; c < C; c++) mx = fmaxf(mx, x[c]);
        float s = 0.f;
        for (int c = 0; c < C; c++) s += __expf(x[c] - mx);
        float lp = x[cls] - mx - __logf(s);
        atomicAdd(&ctl->posCE, -lp);
      }
    }
  }
  __syncthreads();
  for (int i = tid; i < 4096; i += 256) {
    unsigned v = shist[i];
    if (v) atomicAdd(&hist1[i], v);
  }
}

// ---- scan level-1 hist: find bin t1 where cumulative count reaches 3*pnum ----
__global__ __launch_bounds__(256) void k_scan1(const unsigned* __restrict__ hist1,
                                               Ctl* __restrict__ ctl) {
  __shared__ unsigned scanbuf[256];
  int tid = threadIdx.x;
  unsigned rank = 3u * ctl->pnum;
  unsigned h[16];
  unsigned s = 0;
  for (int j = 0; j < 16; j++) { h[j] = hist1[tid * 16 + j]; s += h[j]; }
  scanbuf[tid] = s;
  __syncthreads();
  for (int off = 1; off < 256; off <<= 1) {
    unsigned add = (tid >= off) ? scanbuf[tid - off] : 0u;
    __syncthreads();
    scanbuf[tid] += add;
    __syncthreads();
  }
  unsigned cum = scanbuf[tid] - s;  // exclusive prefix
  for (int j = 0; j < 16; j++) {
    unsigned hh = h[j];
    if (cum < rank && cum + hh >= rank) { ctl->t1 = tid * 16 + j; ctl->r1 = rank - cum; }
    cum += hh;
  }
}

// ---- collect: sum CE for bins < t1 (all selected); compact bin-t1 keys ----
__global__ __launch_bounds__(256) void k_collect(
    const unsigned* __restrict__ keys, Ctl* __restrict__ ctl,
    unsigned* __restrict__ cand) {
  unsigned t1 = ctl->t1;
  int idx = blockIdx.x * 256 + threadIdx.x;
  float v = 0.f;
  unsigned key = 0xFFFFFFFFu;
  if (idx < BN) key = keys[idx];
  unsigned bin = key >> 20;
  if (idx < BN && bin < t1) v = -key2f(key);
  bool isCand = (idx < BN) && (bin == t1);
  // wave-aggregated compaction
  unsigned long long mask = __ballot(isCand);
  int lane = threadIdx.x & 63;
  if (mask) {
    int cnt = __popcll(mask);
    int leader = __ffsll((long long)mask) - 1;
    unsigned base = 0;
    if (lane == leader) base = atomicAdd(&ctl->candCount, (unsigned)cnt);
    base = __shfl(base, leader, 64);
    if (isCand) {
      int r = __popcll(mask & ((1ull << lane) - 1ull));
      cand[base + r] = key;
    }
  }
  // block reduce v
  for (int off = 32; off > 0; off >>= 1) v += __shfl_down(v, off, 64);
  __shared__ float red[4];
  int w = threadIdx.x >> 6;
  if (lane == 0) red[w] = v;
  __syncthreads();
  if (threadIdx.x == 0) {
    float s = red[0] + red[1] + red[2] + red[3];
    if (s != 0.f) atomicAdd(&ctl->negBelow, s);
  }
}

// in-block: find bin (of 1024) where cumulative reaches rank
__device__ void block_find(const unsigned* hist, unsigned rank,
                           unsigned* scanbuf, unsigned* out_bin, unsigned* out_r) {
  int tid = threadIdx.x;
  unsigned h0[4];
  unsigned s = 0;
  for (int j = 0; j < 4; j++) { h0[j] = hist[tid * 4 + j]; s += h0[j]; }
  scanbuf[tid] = s;
  __syncthreads();
  for (int off = 1; off < 256; off <<= 1) {
    unsigned add = (tid >= off) ? scanbuf[tid - off] : 0u;
    __syncthreads();
    scanbuf[tid] += add;
    __syncthreads();
  }
  unsigned cum = scanbuf[tid] - s;
  for (int j = 0; j < 4; j++) {
    unsigned h = h0[j];
    if (cum < rank && cum + h >= rank) { *out_bin = tid * 4 + j; *out_r = rank - cum; }
    cum += h;
  }
  __syncthreads();
}

// ---- select within candidates (all share top-12 bits t1), finalize ----
__global__ __launch_bounds__(256) void k_select(
    const unsigned* __restrict__ cand, Ctl* __restrict__ ctl,
    float* __restrict__ out) {
  __shared__ unsigned hist[1024];
  __shared__ unsigned scanbuf[256];
  __shared__ unsigned s_t2, s_r2, s_t3, s_r3;
  int tid = threadIdx.x;
  unsigned nc = ctl->candCount;
  unsigned r1 = ctl->r1;

  // pass A: hist on bits [19:10]
  for (int i = tid; i < 1024; i += 256) hist[i] = 0;
  __syncthreads();
  for (unsigned i = tid; i < nc; i += 256) atomicAdd(&hist[(cand[i] >> 10) & 0x3FFu], 1u);
  __syncthreads();
  block_find(hist, r1, scanbuf, &s_t2, &s_r2);
  unsigned t2 = s_t2, r2 = s_r2;
  __syncthreads();

  // pass B: sum mids < t2; hist low bits for mid == t2
  for (int i = tid; i < 1024; i += 256) hist[i] = 0;
  __syncthreads();
  float v = 0.f;
  for (unsigned i = tid; i < nc; i += 256) {
    unsigned key = cand[i];
    unsigned mid = (key >> 10) & 0x3FFu;
    if (mid < t2) v += -key2f(key);
    else if (mid == t2) atomicAdd(&hist[key & 0x3FFu], 1u);
  }
  __syncthreads();
  block_find(hist, r2, scanbuf, &s_t3, &s_r3);
  unsigned t3 = s_t3, r3 = s_r3;
  __syncthreads();

  // pass C: sum (mid == t2 && low < t3)
  for (unsigned i = tid; i < nc; i += 256) {
    unsigned key = cand[i];
    if (((key >> 10) & 0x3FFu) == t2 && (key & 0x3FFu) < t3) v += -key2f(key);
  }

  // block reduce v
  for (int off = 32; off > 0; off >>= 1) v += __shfl_down(v, off, 64);
  __shared__ float red[4];
  int lane = tid & 63, w = tid >> 6;
  if (lane == 0) red[w] = v;
  __syncthreads();
  if (tid == 0) {
    float inBin = red[0] + red[1] + red[2] + red[3];
    unsigned t1 = ctl->t1;
    unsigned kth = (t1 << 20) | (t2 << 10) | t3;
    float kv = -key2f(kth);
    float negSum = ctl->negBelow + inBin + (float)r3 * kv;
    unsigned P = ctl->pnum;
    unsigned denom = max(4u * P, 1u);
    out[0] = (ctl->posCE + negSum) / (float)denom;
    unsigned denb = max(4u * ctl->validCount, 1u);
    out[1] = ctl->bboxNum / (float)denb;
  }
}

extern "C" void kernel_launch(void* const* d_in, const int* in_sizes, int n_in,
                              void* d_out, int out_size, void* d_ws, size_t ws_size,
                              hipStream_t stream) {
  const float* conf = (const float*)d_in[0];
  const float* bbox = (const float*)d_in[1];
  const float* target = (const float*)d_in[2];
  const float* pred = (const float*)d_in[3];
  float* out = (float*)d_out;

  char* ws = (char*)d_ws;
  unsigned* keys = (unsigned*)ws;
  size_t off = (size_t)BN * 4;
  unsigned* cand = (unsigned*)(ws + off); off += (size_t)BN * 4;
  unsigned* hist1 = (unsigned*)(ws + off); off += 4096 * 4;
  Ctl* ctl = (Ctl*)(ws + off); off += sizeof(Ctl);

  int nblk = (BN + 255) / 256;
  k_zero<<<1, 256, 0, stream>>>(hist1, ctl);
  k_main<<<dim3((N + 255) / 256, B), 256, 0, stream>>>(conf, bbox, target, pred,
                                                       keys, hist1, ctl);
  k_scan1<<<1, 256, 0, stream>>>(hist1, ctl);
  k_collect<<<dim3(nblk), 256, 0, stream>>>(keys, ctl, cand);
  k_select<<<1, 256, 0, stream>>>(cand, ctl, out);
}